// Round 9
// baseline (1170.277 us; speedup 1.0000x reference)
//
#include <hip/hip_runtime.h>

#define HID   24
#define T_LEN 4096
#define BATCH 1024
#define NB    2                  // batches per wave (one per 32-lane half)
#define TPB   64                 // ONE wave per block; no __syncthreads anywhere
#define NQ    1025               // quad groups: 4100 iterations >= T_LEN+2

typedef __attribute__((ext_vector_type(2))) _Float16 h2v;
typedef __attribute__((ext_vector_type(4))) int      int4v;

__device__ __forceinline__ float dot2f(int p, int w, float acc) {
#if __has_builtin(__builtin_amdgcn_fdot2)
    return __builtin_amdgcn_fdot2(__builtin_bit_cast(h2v, p),
                                  __builtin_bit_cast(h2v, w), acc, false);
#else
    h2v a = __builtin_bit_cast(h2v, p), b = __builtin_bit_cast(h2v, w);
    acc = fmaf((float)a.x, (float)b.x, acc);
    return fmaf((float)a.y, (float)b.y, acc);
#endif
}

__device__ __forceinline__ float dot4(const float4 a, const float4 b, float acc) {
    acc = fmaf(a.x, b.x, acc);
    acc = fmaf(a.y, b.y, acc);
    acc = fmaf(a.z, b.z, acc);
    acc = fmaf(a.w, b.w, acc);
    return acc;
}

// pack two f32 -> packed f16 pair dword
#define PKF(A_, B_)                                                                 \
    (((int)__builtin_bit_cast(unsigned short, (_Float16)(B_)) << 16) |              \
     (int)__builtin_bit_cast(unsigned short, (_Float16)(A_)))

__global__ __launch_bounds__(TPB, 1) void rnn_wave_kernel(
    const float* __restrict__ x,     // [B, T]
    const float* __restrict__ h_in,  // [3, B, 24]
    const float* __restrict__ Wih0, const float* __restrict__ bih0,
    const float* __restrict__ Whh0, const float* __restrict__ bhh0,
    const float* __restrict__ Wih1, const float* __restrict__ bih1,
    const float* __restrict__ Whh1, const float* __restrict__ bhh1,
    const float* __restrict__ Wih2, const float* __restrict__ bih2,
    const float* __restrict__ Whh2, const float* __restrict__ bhh2,
    const float* __restrict__ W1,   const float* __restrict__ b1,
    const float* __restrict__ W2,   const float* __restrict__ b2,
    float* __restrict__ out)         // [1024 (y)] ++ [3*1024*24 (h_final)]
{
    // separate symbols per row -> better LDS alias analysis / finer lgkmcnt waits
    __shared__ __align__(16) _Float16 row0[NB][HID];
    __shared__ __align__(16) _Float16 row1[NB][HID];
    __shared__ __align__(16) _Float16 row2[NB][HID];
    __shared__ float h2f[NB][HID];
    __shared__ float mbuf[NB][HID];

    const int tid  = threadIdx.x;
    const int bl   = tid >> 5;        // batch half
    const int jj   = tid & 31;
    const bool act = (jj < HID);
    const int j    = act ? jj : 0;    // clamped for safe addressing
    const int bg   = blockIdx.x * NB + bl;

    // ---- all three layers' weights in named packed-f16 registers ----
    int4v w0hA, w0hB, w0hC;                         // l0 own-h row
    int4v w1iA, w1iB, w1iC, w1hA, w1hB, w1hC;       // l1 inp + own
    int4v w2iA, w2iB, w2iC, w2hA, w2hB, w2hC;       // l2 inp + own
    float wx0, bias0, bias1, bias2;

#define MK3(ROW, DA, DB, DC) do {                                                   \
        DA = (int4v){PKF((ROW)[0], (ROW)[1]),  PKF((ROW)[2], (ROW)[3]),             \
                     PKF((ROW)[4], (ROW)[5]),  PKF((ROW)[6], (ROW)[7])};            \
        DB = (int4v){PKF((ROW)[8], (ROW)[9]),  PKF((ROW)[10], (ROW)[11]),           \
                     PKF((ROW)[12], (ROW)[13]), PKF((ROW)[14], (ROW)[15])};         \
        DC = (int4v){PKF((ROW)[16], (ROW)[17]), PKF((ROW)[18], (ROW)[19]),          \
                     PKF((ROW)[20], (ROW)[21]), PKF((ROW)[22], (ROW)[23])};         \
    } while (0)

    MK3(Whh0 + j * HID, w0hA, w0hB, w0hC);
    MK3(Wih1 + j * HID, w1iA, w1iB, w1iC);
    MK3(Whh1 + j * HID, w1hA, w1hB, w1hC);
    MK3(Wih2 + j * HID, w2iA, w2iB, w2iC);
    MK3(Whh2 + j * HID, w2hA, w2hB, w2hC);
#undef MK3
    wx0   = Wih0[j];
    bias0 = bih0[j] + bhh0[j];
    bias1 = bih1[j] + bhh1[j];
    bias2 = bih2[j] + bhh2[j];

    // ---- initial state ----
    float cur0 = h_in[(0 * BATCH + bg) * HID + j];
    float cur1 = h_in[(1 * BATCH + bg) * HID + j];
    float cur2 = h_in[(2 * BATCH + bg) * HID + j];
    if (act) {
        row0[bl][j] = (_Float16)cur0;
        row1[bl][j] = (_Float16)cur1;
        row2[bl][j] = (_Float16)cur2;
    }
    // prologue reads (same wave, in-order DS)
    int4v R00 = ((const int4v*)&row0[bl][0])[0];
    int4v R01 = ((const int4v*)&row0[bl][0])[1];
    int4v R02 = ((const int4v*)&row0[bl][0])[2];
    int4v R10 = ((const int4v*)&row1[bl][0])[0];
    int4v R11 = ((const int4v*)&row1[bl][0])[1];
    int4v R12 = ((const int4v*)&row1[bl][0])[2];
    int4v R20 = ((const int4v*)&row2[bl][0])[0];
    int4v R21 = ((const int4v*)&row2[bl][0])[1];
    int4v R22 = ((const int4v*)&row2[bl][0])[2];

    const float* xrow = x + (size_t)bg * T_LEN;
    float4 xqA = *(const float4*)xrow;   // current quad
    float4 xqB;

#define DOT12(V0_, V1_, V2_, W0_, W1_, W2_)                                         \
    a0 = dot2f(V0_.x, W0_.x, a0); a1 = dot2f(V0_.y, W0_.y, a1);                     \
    a2 = dot2f(V0_.z, W0_.z, a2); a3 = dot2f(V0_.w, W0_.w, a3);                     \
    a0 = dot2f(V1_.x, W1_.x, a0); a1 = dot2f(V1_.y, W1_.y, a1);                     \
    a2 = dot2f(V1_.z, W1_.z, a2); a3 = dot2f(V1_.w, W1_.w, a3);                     \
    a0 = dot2f(V2_.x, W2_.x, a0); a1 = dot2f(V2_.y, W2_.y, a1);                     \
    a2 = dot2f(V2_.z, W2_.z, a2); a3 = dot2f(V2_.w, W2_.w, a3);

    // ---- barrier-free fused pipeline with rotated row traffic ----
    // iter u: l0(u) uses R0=h0(u-1); l1(u-1) uses R0,R1; l2(u-2) uses R1,R2.
    // After each layer's compute: write its row, immediately issue next read;
    // the RAW hides under the NEXT layer's dots.
    for (int q = 0; q < NQ; ++q) {
        const int u0 = q * 4;
        const int nxt = (u0 + 4 <= T_LEN - 4) ? (u0 + 4) : (T_LEN - 4);
        xqB = *(const float4*)(xrow + nxt);   // prefetch next x quad

        #pragma unroll
        for (int s = 0; s < 4; ++s) {
            const int u = u0 + s;
            const float xv = (s == 0) ? xqA.x : (s == 1) ? xqA.y
                           : (s == 2) ? xqA.z : xqA.w;

            float a0, a1, a2, a3;
            // ---- layer 0 (step u): own dots from regs ----
            a0 = fmaf(wx0, xv, bias0); a1 = 0.f; a2 = 0.f; a3 = 0.f;
            DOT12(R00, R01, R02, w0hA, w0hB, w0hC);
            const float v0 = fmaxf((a0 + a1) + (a2 + a3), 0.f);
            cur0 = (u < T_LEN) ? v0 : cur0;
            // ---- layer 1 (step u-1): uses R0 (pre-update h0), R1 ----
            a0 = bias1; a1 = 0.f; a2 = 0.f; a3 = 0.f;
            DOT12(R00, R01, R02, w1iA, w1iB, w1iC);
            // publish h0(u) and issue its read-back; RAW hides under l1-own + l2 dots
            if (act) row0[bl][j] = (_Float16)cur0;
            int4v N00 = ((const int4v*)&row0[bl][0])[0];
            int4v N01 = ((const int4v*)&row0[bl][0])[1];
            int4v N02 = ((const int4v*)&row0[bl][0])[2];
            DOT12(R10, R11, R12, w1hA, w1hB, w1hC);
            const float v1 = fmaxf((a0 + a1) + (a2 + a3), 0.f);
            cur1 = (u >= 1 && u <= T_LEN) ? v1 : cur1;
            // ---- layer 2 (step u-2): uses R1 (pre-update h1), R2 ----
            a0 = bias2; a1 = 0.f; a2 = 0.f; a3 = 0.f;
            DOT12(R10, R11, R12, w2iA, w2iB, w2iC);
            if (act) row1[bl][j] = (_Float16)cur1;
            int4v N10 = ((const int4v*)&row1[bl][0])[0];
            int4v N11 = ((const int4v*)&row1[bl][0])[1];
            int4v N12 = ((const int4v*)&row1[bl][0])[2];
            DOT12(R20, R21, R22, w2hA, w2hB, w2hC);
            const float v2 = fmaxf((a0 + a1) + (a2 + a3), 0.f);
            cur2 = (u >= 2 && u <= T_LEN + 1) ? v2 : cur2;
            if (act) row2[bl][j] = (_Float16)cur2;
            int4v N20 = ((const int4v*)&row2[bl][0])[0];
            int4v N21 = ((const int4v*)&row2[bl][0])[1];
            int4v N22 = ((const int4v*)&row2[bl][0])[2];
            // rotate
            R00 = N00; R01 = N01; R02 = N02;
            R10 = N10; R11 = N11; R12 = N12;
            R20 = N20; R21 = N21; R22 = N22;
        }
        xqA = xqB;
    }
#undef DOT12

    // ---- h_final from f32 running values ----
    if (act) {
        out[BATCH + (size_t)(0 * BATCH + bg) * HID + j] = cur0;
        out[BATCH + (size_t)(1 * BATCH + bg) * HID + j] = cur1;
        out[BATCH + (size_t)(2 * BATCH + bg) * HID + j] = cur2;
        h2f[bl][j] = cur2;
    }
    // same wave -> ordered
    if (act) {
        const float4* w1r = (const float4*)(W1 + j * HID);
        const float4* hv  = (const float4*)&h2f[bl][0];
        float a = b1[j];
        a = dot4(w1r[0], hv[0], a); a = dot4(w1r[1], hv[1], a);
        a = dot4(w1r[2], hv[2], a); a = dot4(w1r[3], hv[3], a);
        a = dot4(w1r[4], hv[4], a); a = dot4(w1r[5], hv[5], a);
        mbuf[bl][j] = fmaxf(a, 0.f);
    }
    if (jj == 0) {
        float a = b2[0];
        #pragma unroll
        for (int k = 0; k < HID; ++k) a = fmaf(W2[k], mbuf[bl][k], a);
        out[bg] = fmaxf(a, 0.f);
    }
}

extern "C" void kernel_launch(void* const* d_in, const int* in_sizes, int n_in,
                              void* d_out, int out_size, void* d_ws, size_t ws_size,
                              hipStream_t stream) {
    const float* x    = (const float*)d_in[0];
    const float* h_in = (const float*)d_in[1];
    const float* Wih0 = (const float*)d_in[2];
    const float* bih0 = (const float*)d_in[3];
    const float* Whh0 = (const float*)d_in[4];
    const float* bhh0 = (const float*)d_in[5];
    const float* Wih1 = (const float*)d_in[6];
    const float* bih1 = (const float*)d_in[7];
    const float* Whh1 = (const float*)d_in[8];
    const float* bhh1 = (const float*)d_in[9];
    const float* Wih2 = (const float*)d_in[10];
    const float* bih2 = (const float*)d_in[11];
    const float* Whh2 = (const float*)d_in[12];
    const float* bhh2 = (const float*)d_in[13];
    const float* W1   = (const float*)d_in[14];
    const float* b1   = (const float*)d_in[15];
    const float* W2   = (const float*)d_in[16];
    const float* b2   = (const float*)d_in[17];
    float* out = (float*)d_out;

    dim3 grid(BATCH / NB);   // 512 single-wave blocks
    dim3 block(TPB);
    hipLaunchKernelGGL(rnn_wave_kernel, grid, block, 0, stream,
                       x, h_in, Wih0, bih0, Whh0, bhh0,
                       Wih1, bih1, Whh1, bhh1, Wih2, bih2, Whh2, bhh2,
                       W1, b1, W2, b2, out);
}

// Round 10
// 1052.395 us; speedup vs baseline: 1.1120x; 1.1120x over previous
//
#include <hip/hip_runtime.h>

#define HID   24
#define T_LEN 4096
#define BATCH 1024
#define NB    2                  // batches per wave (one per 32-lane half)
#define TPB   64                 // ONE wave per block; no __syncthreads anywhere
#define NQ    1025               // 4100 iterations >= T_LEN+2

typedef __attribute__((ext_vector_type(2))) _Float16 h2v;
typedef __attribute__((ext_vector_type(2))) unsigned int uint2v;

#if __has_builtin(__builtin_amdgcn_fdot2)
__device__ __forceinline__ float dot2f(int p, int w, float acc) {
    return __builtin_amdgcn_fdot2(__builtin_bit_cast(h2v, p),
                                  __builtin_bit_cast(h2v, w), acc, false);
}
#else
__device__ __forceinline__ float dot2f(int p, int w, float acc) {
    h2v a = __builtin_bit_cast(h2v, p), b = __builtin_bit_cast(h2v, w);
    acc = fmaf((float)a.x, (float)b.x, acc);
    return fmaf((float)a.y, (float)b.y, acc);
}
#endif

__device__ __forceinline__ float dot4(const float4 a, const float4 b, float acc) {
    acc = fmaf(a.x, b.x, acc);
    acc = fmaf(a.y, b.y, acc);
    acc = fmaf(a.z, b.z, acc);
    return fmaf(a.w, b.w, acc);
}

// DPP row-rotate by N within 16-lane rows (VALU pipe)
template<int N> __device__ __forceinline__ int rr(int v) {
    return __builtin_amdgcn_mov_dpp(v, 0x120 + N, 0xF, 0xF, false);
}
// quad_perm [1,0,3,2]: neighbor swap within pairs
__device__ __forceinline__ int qp_nbr(int v) {
    return __builtin_amdgcn_mov_dpp(v, 0xB1, 0xF, 0xF, false);
}

// pack one f16 weight pair for pair index m, with odd-lane half swap
__device__ __forceinline__ int pkw(const float* row, int m, int par) {
    float wl = row[2 * m], wh = row[2 * m + 1];
    if (par) { float t = wl; wl = wh; wh = t; }
    const unsigned short ul = __builtin_bit_cast(unsigned short, (_Float16)wl);
    const unsigned short uh = __builtin_bit_cast(unsigned short, (_Float16)wh);
    return ((int)uh << 16) | (int)ul;
}

template<bool USE_BP>
__device__ __forceinline__ void run_rnn(
    const float* __restrict__ x, const float* __restrict__ h_in,
    const float* __restrict__ Wih0, const float* __restrict__ bih0,
    const float* __restrict__ Whh0, const float* __restrict__ bhh0,
    const float* __restrict__ Wih1, const float* __restrict__ bih1,
    const float* __restrict__ Whh1, const float* __restrict__ bhh1,
    const float* __restrict__ Wih2, const float* __restrict__ bih2,
    const float* __restrict__ Whh2, const float* __restrict__ bhh2,
    const float* __restrict__ W1,   const float* __restrict__ b1,
    const float* __restrict__ W2,   const float* __restrict__ b2,
    float* __restrict__ out,
    const int lane, const int dir, const bool flip,
    float (*h2f)[HID], float (*mbuf)[HID])
{
    const int bl  = lane >> 5;                  // batch half
    const int jj  = lane & 31;
    const bool act = (jj < HID);
    const int uL  = act ? jj : (jj - 8);        // lanes 24-31 duplicate units 16-23
    const int par = lane & 1;
    const int bg  = blockIdx.x * NB + bl;
    const int alo = (((lane & 32) | (lane & 15)) << 2);        // bpermute fallback addrs
    const int ahi = (((lane & 32) | 16 | (lane & 15)) << 2);

    // ---- per-lane permuted packed-f16 weights (order matches DPP gather) ----
    int w0h[12], w1i[12], w1h[12], w2i[12], w2h[12];
    {
        const float* r0h = Whh0 + uL * HID;
        const float* r1i = Wih1 + uL * HID;
        const float* r1h = Whh1 + uL * HID;
        const float* r2i = Wih2 + uL * HID;
        const float* r2h = Whh2 + uL * HID;
        #pragma unroll
        for (int k = 0; k < 12; ++k) {
            const int r = (k < 8) ? (2 * k) : (2 * (k - 8));
            const int s = (((lane & 15) + dir * r) & 15);
            const int m = (k < 8) ? (s >> 1) : (8 + ((s >> 1) & 3));
            w0h[k] = pkw(r0h, m, par);
            w1i[k] = pkw(r1i, m, par);
            w1h[k] = pkw(r1h, m, par);
            w2i[k] = pkw(r2i, m, par);
            w2h[k] = pkw(r2h, m, par);
        }
    }
    const float wx0   = Wih0[uL];
    const float bias0 = bih0[uL] + bhh0[uL];
    const float bias1 = bih1[uL] + bhh1[uL];
    const float bias2 = bih2[uL] + bhh2[uL];

    float cur0 = h_in[(0 * BATCH + bg) * HID + uL];
    float cur1 = h_in[(1 * BATCH + bg) * HID + uL];
    float cur2 = h_in[(2 * BATCH + bg) * HID + uL];

// all-VALU 24-wide broadcast: cur (f32 per lane) -> 12 pair dwords in every lane
#define GATHER(CF_, R_) do {                                                        \
    int hc_ = (int)(unsigned)__builtin_bit_cast(unsigned short, (_Float16)(CF_));   \
    int pk_ = (qp_nbr(hc_) << 16) | hc_;                                            \
    int ea_, eb_;                                                                   \
    if constexpr (USE_BP) {                                                         \
        ea_ = __builtin_amdgcn_ds_bpermute(alo, pk_);                               \
        eb_ = __builtin_amdgcn_ds_bpermute(ahi, pk_);                               \
    } else {                                                                        \
        uint2v s_ = __builtin_amdgcn_permlane16_swap((unsigned)pk_, (unsigned)pk_,  \
                                                     false, false);                 \
        ea_ = flip ? (int)s_.y : (int)s_.x;                                         \
        eb_ = flip ? (int)s_.x : (int)s_.y;                                         \
    }                                                                               \
    R_[0] = ea_;        R_[1] = rr<2>(ea_);   R_[2] = rr<4>(ea_);                   \
    R_[3] = rr<6>(ea_); R_[4] = rr<8>(ea_);   R_[5] = rr<10>(ea_);                  \
    R_[6] = rr<12>(ea_); R_[7] = rr<14>(ea_);                                       \
    R_[8] = eb_;        R_[9] = rr<2>(eb_);   R_[10] = rr<4>(eb_);                  \
    R_[11] = rr<6>(eb_);                                                            \
} while (0)

#define DOT12(R_, W_, A0_, A1_)                                                     \
    A0_ = dot2f(R_[0], W_[0], A0_);   A1_ = dot2f(R_[1], W_[1], A1_);               \
    A0_ = dot2f(R_[2], W_[2], A0_);   A1_ = dot2f(R_[3], W_[3], A1_);               \
    A0_ = dot2f(R_[4], W_[4], A0_);   A1_ = dot2f(R_[5], W_[5], A1_);               \
    A0_ = dot2f(R_[6], W_[6], A0_);   A1_ = dot2f(R_[7], W_[7], A1_);               \
    A0_ = dot2f(R_[8], W_[8], A0_);   A1_ = dot2f(R_[9], W_[9], A1_);               \
    A0_ = dot2f(R_[10], W_[10], A0_); A1_ = dot2f(R_[11], W_[11], A1_);

    int R0[12], R1[12], R2[12];
    GATHER(cur0, R0);
    GATHER(cur1, R1);
    GATHER(cur2, R2);

    const float* xrow = x + (size_t)bg * T_LEN;
    float4 xqA = *(const float4*)xrow;
    float4 xqB;

    // ---- barrier-free, LDS-free fused pipeline: iter u -> l0(u), l1(u-1), l2(u-2) ----
    for (int q = 0; q < NQ; ++q) {
        const int u0 = q * 4;
        const int nxt = (u0 + 4 <= T_LEN - 4) ? (u0 + 4) : (T_LEN - 4);
        xqB = *(const float4*)(xrow + nxt);

        #pragma unroll
        for (int s = 0; s < 4; ++s) {
            const int u = u0 + s;
            const float xv = (s == 0) ? xqA.x : (s == 1) ? xqA.y
                           : (s == 2) ? xqA.z : xqA.w;
            float a0, a1, a2, a3;
            // layer 0 (step u)
            a0 = fmaf(wx0, xv, bias0); a1 = 0.f;
            DOT12(R0, w0h, a0, a1);
            const float v0 = fmaxf(a0 + a1, 0.f);
            // layer 1 (step u-1)
            a0 = bias1; a1 = 0.f; a2 = 0.f; a3 = 0.f;
            DOT12(R0, w1i, a0, a1);
            DOT12(R1, w1h, a2, a3);
            const float v1 = fmaxf((a0 + a1) + (a2 + a3), 0.f);
            // layer 2 (step u-2)
            a0 = bias2; a1 = 0.f; a2 = 0.f; a3 = 0.f;
            DOT12(R1, w2i, a0, a1);
            DOT12(R2, w2h, a2, a3);
            const float v2 = fmaxf((a0 + a1) + (a2 + a3), 0.f);
            // latch (u wave-uniform)
            cur0 = (u < T_LEN) ? v0 : cur0;
            cur1 = (u >= 1 && u <= T_LEN) ? v1 : cur1;
            cur2 = (u >= 2 && u <= T_LEN + 1) ? v2 : cur2;
            // broadcast for next iteration (pure VALU)
            GATHER(cur0, R0);
            GATHER(cur1, R1);
            GATHER(cur2, R2);
        }
        xqA = xqB;
    }
#undef DOT12
#undef GATHER

    // ---- h_final from f32 running values ----
    if (act) {
        out[BATCH + (size_t)(0 * BATCH + bg) * HID + uL] = cur0;
        out[BATCH + (size_t)(1 * BATCH + bg) * HID + uL] = cur1;
        out[BATCH + (size_t)(2 * BATCH + bg) * HID + uL] = cur2;
        h2f[bl][uL] = cur2;
    }
    // same wave -> DS in-order; no barrier needed
    if (act) {
        const float4* w1r = (const float4*)(W1 + uL * HID);
        const float4* hv  = (const float4*)&h2f[bl][0];
        float a = b1[uL];
        a = dot4(w1r[0], hv[0], a); a = dot4(w1r[1], hv[1], a);
        a = dot4(w1r[2], hv[2], a); a = dot4(w1r[3], hv[3], a);
        a = dot4(w1r[4], hv[4], a); a = dot4(w1r[5], hv[5], a);
        mbuf[bl][uL] = fmaxf(a, 0.f);
    }
    if (jj == 0) {
        float a = b2[0];
        #pragma unroll
        for (int k = 0; k < HID; ++k) a = fmaf(W2[k], mbuf[bl][k], a);
        out[bg] = fmaxf(a, 0.f);
    }
}

__global__ __launch_bounds__(TPB, 1) void rnn_dpp_kernel(
    const float* __restrict__ x, const float* __restrict__ h_in,
    const float* __restrict__ Wih0, const float* __restrict__ bih0,
    const float* __restrict__ Whh0, const float* __restrict__ bhh0,
    const float* __restrict__ Wih1, const float* __restrict__ bih1,
    const float* __restrict__ Whh1, const float* __restrict__ bhh1,
    const float* __restrict__ Wih2, const float* __restrict__ bih2,
    const float* __restrict__ Whh2, const float* __restrict__ bhh2,
    const float* __restrict__ W1,   const float* __restrict__ b1,
    const float* __restrict__ W2,   const float* __restrict__ b2,
    float* __restrict__ out)
{
    __shared__ float h2f[NB][HID];
    __shared__ float mbuf[NB][HID];
    const int lane = threadIdx.x & 63;

    // probe DPP row_ror direction (HW semantics): lane0 sees 2 (src=i+N) or 14 (src=i-N)
    int pv = lane;
    const int d0 = __builtin_amdgcn_readfirstlane(rr<2>(pv));
    const int dir = (d0 == 2) ? 1 : -1;

#if __has_builtin(__builtin_amdgcn_permlane16_swap)
    // probe permlane16_swap orientation; fall back to ds_bpermute if unexpected
    uint2v sw = __builtin_amdgcn_permlane16_swap((unsigned)pv, (unsigned)pv, false, false);
    const int s0  = __builtin_amdgcn_readlane((int)sw.x, 0);
    const int s16 = __builtin_amdgcn_readlane((int)sw.x, 16);
    const bool ok   = (s0 == 0 && s16 == 0) || (s0 == 16 && s16 == 16);
    const bool flip = (s0 == 16);
    if (ok) {
        run_rnn<false>(x, h_in, Wih0, bih0, Whh0, bhh0, Wih1, bih1, Whh1, bhh1,
                       Wih2, bih2, Whh2, bhh2, W1, b1, W2, b2, out,
                       lane, dir, flip, h2f, mbuf);
    } else {
        run_rnn<true>(x, h_in, Wih0, bih0, Whh0, bhh0, Wih1, bih1, Whh1, bhh1,
                      Wih2, bih2, Whh2, bhh2, W1, b1, W2, b2, out,
                      lane, dir, false, h2f, mbuf);
    }
#else
    run_rnn<true>(x, h_in, Wih0, bih0, Whh0, bhh0, Wih1, bih1, Whh1, bhh1,
                  Wih2, bih2, Whh2, bhh2, W1, b1, W2, b2, out,
                  lane, dir, false, h2f, mbuf);
#endif
}

extern "C" void kernel_launch(void* const* d_in, const int* in_sizes, int n_in,
                              void* d_out, int out_size, void* d_ws, size_t ws_size,
                              hipStream_t stream) {
    const float* x    = (const float*)d_in[0];
    const float* h_in = (const float*)d_in[1];
    const float* Wih0 = (const float*)d_in[2];
    const float* bih0 = (const float*)d_in[3];
    const float* Whh0 = (const float*)d_in[4];
    const float* bhh0 = (const float*)d_in[5];
    const float* Wih1 = (const float*)d_in[6];
    const float* bih1 = (const float*)d_in[7];
    const float* Whh1 = (const float*)d_in[8];
    const float* bhh1 = (const float*)d_in[9];
    const float* Wih2 = (const float*)d_in[10];
    const float* bih2 = (const float*)d_in[11];
    const float* Whh2 = (const float*)d_in[12];
    const float* bhh2 = (const float*)d_in[13];
    const float* W1   = (const float*)d_in[14];
    const float* b1   = (const float*)d_in[15];
    const float* W2   = (const float*)d_in[16];
    const float* b2   = (const float*)d_in[17];
    float* out = (float*)d_out;

    dim3 grid(BATCH / NB);   // 512 single-wave blocks -> 2 per CU
    dim3 block(TPB);
    hipLaunchKernelGGL(rnn_dpp_kernel, grid, block, 0, stream,
                       x, h_in, Wih0, bih0, Whh0, bhh0,
                       Wih1, bih1, Whh1, bhh1, Wih2, bih2, Whh2, bhh2,
                       W1, b1, W2, b2, out);
}

// Round 11
// 799.698 us; speedup vs baseline: 1.4634x; 1.3160x over previous
//
#include <hip/hip_runtime.h>

#define HID   24
#define T_LEN 4096
#define BATCH 1024
#define NB    2                  // batches per block (one per 32-lane half of each wave)
#define K     16                 // timesteps per chunk (pipeline skew per layer)
#define NC    (T_LEN / K)        // 256 active chunks per layer
#define CTOT  (NC + 2)           // 258 ticks total (3-layer skew)
#define TPB   192                // 3 waves: wave w == layer w

typedef __attribute__((ext_vector_type(2))) _Float16 h2v;
typedef __attribute__((ext_vector_type(4))) int      int4v;
typedef __attribute__((ext_vector_type(2))) unsigned int uint2v;

#if __has_builtin(__builtin_amdgcn_fdot2)
__device__ __forceinline__ float dot2f(int p, int w, float acc) {
    return __builtin_amdgcn_fdot2(__builtin_bit_cast(h2v, p),
                                  __builtin_bit_cast(h2v, w), acc, false);
}
#else
__device__ __forceinline__ float dot2f(int p, int w, float acc) {
    h2v a = __builtin_bit_cast(h2v, p), b = __builtin_bit_cast(h2v, w);
    acc = fmaf((float)a.x, (float)b.x, acc);
    return fmaf((float)a.y, (float)b.y, acc);
}
#endif

__device__ __forceinline__ float dot4(const float4 a, const float4 b, float acc) {
    acc = fmaf(a.x, b.x, acc);
    acc = fmaf(a.y, b.y, acc);
    acc = fmaf(a.z, b.z, acc);
    return fmaf(a.w, b.w, acc);
}

// DPP row-rotate by N within 16-lane rows (VALU pipe)
template<int N> __device__ __forceinline__ int rr(int v) {
    return __builtin_amdgcn_mov_dpp(v, 0x120 + N, 0xF, 0xF, false);
}
// quad_perm [1,0,3,2]: neighbor swap within pairs
__device__ __forceinline__ int qp_nbr(int v) {
    return __builtin_amdgcn_mov_dpp(v, 0xB1, 0xF, 0xF, false);
}

// pack two f32 -> packed f16 pair dword (natural order)
#define PKF(A_, B_)                                                                 \
    (((int)__builtin_bit_cast(unsigned short, (_Float16)(B_)) << 16) |              \
     (int)__builtin_bit_cast(unsigned short, (_Float16)(A_)))

// pack one f16 weight pair for pair index m, with odd-lane half swap
__device__ __forceinline__ int pkw(const float* row, int m, int par) {
    float wl = row[2 * m], wh = row[2 * m + 1];
    if (par) { float t = wl; wl = wh; wh = t; }
    const unsigned short ul = __builtin_bit_cast(unsigned short, (_Float16)wl);
    const unsigned short uh = __builtin_bit_cast(unsigned short, (_Float16)wh);
    return ((int)uh << 16) | (int)ul;
}

template<bool USE_BP>
__device__ __forceinline__ void run_rnn(
    const float* __restrict__ x, const float* __restrict__ h_in,
    const float* __restrict__ Wih0, const float* __restrict__ bih0,
    const float* __restrict__ Whh0, const float* __restrict__ bhh0,
    const float* __restrict__ Wih1, const float* __restrict__ bih1,
    const float* __restrict__ Whh1, const float* __restrict__ bhh1,
    const float* __restrict__ Wih2, const float* __restrict__ bih2,
    const float* __restrict__ Whh2, const float* __restrict__ bhh2,
    const float* __restrict__ W1,   const float* __restrict__ b1,
    const float* __restrict__ W2,   const float* __restrict__ b2,
    float* __restrict__ out, const int dir, const bool flip,
    _Float16* pub0, _Float16* pub1, float (*h2f)[HID], float (*mbuf)[HID])
{
    const int tid  = threadIdx.x;
    const int l    = tid >> 6;        // wave == layer
    const int lane = tid & 63;
    const int bl   = lane >> 5;       // batch half
    const int jj   = lane & 31;
    const bool act = (jj < HID);
    const int uL   = act ? jj : (jj - 8);   // lanes 24-31 duplicate units 16-23
    const int par  = lane & 1;
    const int bg   = blockIdx.x * NB + bl;
    const int alo  = (((lane & 32) | (lane & 15)) << 2);       // bpermute fallback
    const int ahi  = (((lane & 32) | 16 | (lane & 15)) << 2);

    // ---- own-h weights, permuted to match the DPP gather rotation order ----
    int wP[12];
    {
        const float* ownrow = ((l == 0) ? Whh0 : (l == 1) ? Whh1 : Whh2) + uL * HID;
        #pragma unroll
        for (int k = 0; k < 12; ++k) {
            const int r = (k < 8) ? (2 * k) : (2 * (k - 8));
            const int s = (((lane & 15) + dir * r) & 15);
            const int m = (k < 8) ? (s >> 1) : (8 + ((s >> 1) & 3));
            wP[k] = pkw(ownrow, m, par);
        }
    }
    // ---- input-from-below weights, natural packed order (layers 1,2) ----
    int4v wiA = {0,0,0,0}, wiB = {0,0,0,0}, wiC = {0,0,0,0};
    if (l >= 1) {
        const float* r_ = ((l == 1) ? Wih1 : Wih2) + uL * HID;
        wiA = (int4v){PKF(r_[0], r_[1]),   PKF(r_[2], r_[3]),
                      PKF(r_[4], r_[5]),   PKF(r_[6], r_[7])};
        wiB = (int4v){PKF(r_[8], r_[9]),   PKF(r_[10], r_[11]),
                      PKF(r_[12], r_[13]), PKF(r_[14], r_[15])};
        wiC = (int4v){PKF(r_[16], r_[17]), PKF(r_[18], r_[19]),
                      PKF(r_[20], r_[21]), PKF(r_[22], r_[23])};
    }
    const float wx0  = Wih0[uL];
    const float bias = (l == 0) ? (bih0[uL] + bhh0[uL])
                     : (l == 1) ? (bih1[uL] + bhh1[uL])
                                : (bih2[uL] + bhh2[uL]);

    float cur = h_in[(l * BATCH + bg) * HID + uL];

// all-VALU 24-wide broadcast: cur (f32 per lane) -> 12 pair dwords in every lane
#define GATHER(CF_, R_) do {                                                        \
    int hc_ = (int)(unsigned)__builtin_bit_cast(unsigned short, (_Float16)(CF_));   \
    int pk_ = (qp_nbr(hc_) << 16) | hc_;                                            \
    int ea_, eb_;                                                                   \
    if constexpr (USE_BP) {                                                         \
        ea_ = __builtin_amdgcn_ds_bpermute(alo, pk_);                               \
        eb_ = __builtin_amdgcn_ds_bpermute(ahi, pk_);                               \
    } else {                                                                        \
        uint2v s_ = __builtin_amdgcn_permlane16_swap((unsigned)pk_, (unsigned)pk_,  \
                                                     false, false);                 \
        ea_ = flip ? (int)s_.y : (int)s_.x;                                         \
        eb_ = flip ? (int)s_.x : (int)s_.y;                                         \
    }                                                                               \
    R_[0] = ea_;         R_[1] = rr<2>(ea_);   R_[2] = rr<4>(ea_);                  \
    R_[3] = rr<6>(ea_);  R_[4] = rr<8>(ea_);   R_[5] = rr<10>(ea_);                 \
    R_[6] = rr<12>(ea_); R_[7] = rr<14>(ea_);                                       \
    R_[8] = eb_;         R_[9] = rr<2>(eb_);   R_[10] = rr<4>(eb_);                 \
    R_[11] = rr<6>(eb_);                                                            \
} while (0)

#define DOT12P(R_, W_, A0_, A1_)                                                    \
    A0_ = dot2f(R_[0], W_[0], A0_);   A1_ = dot2f(R_[1], W_[1], A1_);               \
    A0_ = dot2f(R_[2], W_[2], A0_);   A1_ = dot2f(R_[3], W_[3], A1_);               \
    A0_ = dot2f(R_[4], W_[4], A0_);   A1_ = dot2f(R_[5], W_[5], A1_);               \
    A0_ = dot2f(R_[6], W_[6], A0_);   A1_ = dot2f(R_[7], W_[7], A1_);               \
    A0_ = dot2f(R_[8], W_[8], A0_);   A1_ = dot2f(R_[9], W_[9], A1_);               \
    A0_ = dot2f(R_[10], W_[10], A0_); A1_ = dot2f(R_[11], W_[11], A1_);

#define DOT12N(V0_, V1_, V2_, W0_, W1_, W2_, A0_, A1_)                              \
    A0_ = dot2f(V0_.x, W0_.x, A0_); A1_ = dot2f(V0_.y, W0_.y, A1_);                 \
    A0_ = dot2f(V0_.z, W0_.z, A0_); A1_ = dot2f(V0_.w, W0_.w, A1_);                 \
    A0_ = dot2f(V1_.x, W1_.x, A0_); A1_ = dot2f(V1_.y, W1_.y, A1_);                 \
    A0_ = dot2f(V1_.z, W1_.z, A0_); A1_ = dot2f(V1_.w, W1_.w, A1_);                 \
    A0_ = dot2f(V2_.x, W2_.x, A0_); A1_ = dot2f(V2_.y, W2_.y, A1_);                 \
    A0_ = dot2f(V2_.z, W2_.z, A0_); A1_ = dot2f(V2_.w, W2_.w, A1_);

    int R[12];
    GATHER(cur, R);

    // x quads in registers (layer-0 wave)
    const float* xrow = x + (size_t)bg * T_LEN;
    float4 xq0, xq1, xq2, xq3;
    xq0 = xq1 = xq2 = xq3 = make_float4(0.f, 0.f, 0.f, 0.f);
    if (l == 0) {
        const float4* xr = (const float4*)xrow;
        xq0 = xr[0]; xq1 = xr[1]; xq2 = xr[2]; xq3 = xr[3];
    }
#define XV(S)                                                                       \
    ((S) == 0 ? xq0.x : (S) == 1 ? xq0.y : (S) == 2 ? xq0.z : (S) == 3 ? xq0.w      \
   : (S) == 4 ? xq1.x : (S) == 5 ? xq1.y : (S) == 6 ? xq1.z : (S) == 7 ? xq1.w      \
   : (S) == 8 ? xq2.x : (S) == 9 ? xq2.y : (S) == 10 ? xq2.z : (S) == 11 ? xq2.w    \
   : (S) == 12 ? xq3.x : (S) == 13 ? xq3.y : (S) == 14 ? xq3.z : xq3.w)

    __syncthreads();

    // ---- chunked, layer-skewed scan: chunk c, layer l handles t in [(c-l)*K, +K) ----
    for (int c = 0; c < CTOT; ++c) {
        const int wp = c & 1, rp = wp ^ 1;
        if (l == 0) {
            if (c < NC) {
                float4 xn0, xn1, xn2, xn3;
                const bool pf = (c + 1 < NC);
                if (pf) {
                    const float4* xn = (const float4*)(xrow + (size_t)(c + 1) * K);
                    xn0 = xn[0]; xn1 = xn[1]; xn2 = xn[2]; xn3 = xn[3];
                }
                _Float16* dst = pub0 + ((size_t)(wp * NB + bl) * K) * HID;
                #pragma unroll
                for (int s = 0; s < K; ++s) {
                    float a0 = fmaf(wx0, XV(s), bias), a1 = 0.f;
                    DOT12P(R, wP, a0, a1);
                    cur = fmaxf(a0 + a1, 0.f);
                    if (act) dst[s * HID + uL] = (_Float16)cur;
                    GATHER(cur, R);
                }
                if (pf) { xq0 = xn0; xq1 = xn1; xq2 = xn2; xq3 = xn3; }
            }
        } else if (l == 1) {
            if (c >= 1 && c < 1 + NC) {
                const _Float16* src = pub0 + ((size_t)(rp * NB + bl) * K) * HID;
                _Float16* dst = pub1 + ((size_t)(wp * NB + bl) * K) * HID;
                int4v iA0 = ((const int4v*)src)[0];
                int4v iA1 = ((const int4v*)src)[1];
                int4v iA2 = ((const int4v*)src)[2];
                #pragma unroll
                for (int s = 0; s < K; ++s) {
                    int4v iB0, iB1, iB2;
                    if (s + 1 < K) {
                        const int4v* nr = (const int4v*)(src + (s + 1) * HID);
                        iB0 = nr[0]; iB1 = nr[1]; iB2 = nr[2];
                    }
                    float a0 = bias, a1 = 0.f, a2 = 0.f, a3 = 0.f;
                    DOT12N(iA0, iA1, iA2, wiA, wiB, wiC, a0, a1);
                    DOT12P(R, wP, a2, a3);
                    cur = fmaxf((a0 + a1) + (a2 + a3), 0.f);
                    if (act) dst[s * HID + uL] = (_Float16)cur;
                    GATHER(cur, R);
                    if (s + 1 < K) { iA0 = iB0; iA1 = iB1; iA2 = iB2; }
                }
            }
        } else {
            if (c >= 2 && c < 2 + NC) {
                const _Float16* src = pub1 + ((size_t)(rp * NB + bl) * K) * HID;
                int4v iA0 = ((const int4v*)src)[0];
                int4v iA1 = ((const int4v*)src)[1];
                int4v iA2 = ((const int4v*)src)[2];
                #pragma unroll
                for (int s = 0; s < K; ++s) {
                    int4v iB0, iB1, iB2;
                    if (s + 1 < K) {
                        const int4v* nr = (const int4v*)(src + (s + 1) * HID);
                        iB0 = nr[0]; iB1 = nr[1]; iB2 = nr[2];
                    }
                    float a0 = bias, a1 = 0.f, a2 = 0.f, a3 = 0.f;
                    DOT12N(iA0, iA1, iA2, wiA, wiB, wiC, a0, a1);
                    DOT12P(R, wP, a2, a3);
                    cur = fmaxf((a0 + a1) + (a2 + a3), 0.f);
                    GATHER(cur, R);
                    if (s + 1 < K) { iA0 = iB0; iA1 = iB1; iA2 = iB2; }
                }
            }
        }
        __syncthreads();
    }
#undef XV
#undef DOT12N
#undef DOT12P
#undef GATHER

    // ---- h_final from f32 running values ----
    if (act) out[BATCH + (size_t)(l * BATCH + bg) * HID + uL] = cur;

    // ---- MLP head on h2(T-1) ----
    if (l == 2 && act) h2f[bl][uL] = cur;
    __syncthreads();
    if (l == 2 && act) {
        const float4* w1r = (const float4*)(W1 + uL * HID);
        const float4* hv  = (const float4*)&h2f[bl][0];
        float a = b1[uL];
        a = dot4(w1r[0], hv[0], a); a = dot4(w1r[1], hv[1], a);
        a = dot4(w1r[2], hv[2], a); a = dot4(w1r[3], hv[3], a);
        a = dot4(w1r[4], hv[4], a); a = dot4(w1r[5], hv[5], a);
        mbuf[bl][uL] = fmaxf(a, 0.f);
    }
    __syncthreads();
    if (l == 2 && jj == 0) {
        float a = b2[0];
        #pragma unroll
        for (int k = 0; k < HID; ++k) a = fmaf(W2[k], mbuf[bl][k], a);
        out[bg] = fmaxf(a, 0.f);
    }
}

__global__ __launch_bounds__(TPB, 1) void rnn_hyb_kernel(
    const float* __restrict__ x, const float* __restrict__ h_in,
    const float* __restrict__ Wih0, const float* __restrict__ bih0,
    const float* __restrict__ Whh0, const float* __restrict__ bhh0,
    const float* __restrict__ Wih1, const float* __restrict__ bih1,
    const float* __restrict__ Whh1, const float* __restrict__ bhh1,
    const float* __restrict__ Wih2, const float* __restrict__ bih2,
    const float* __restrict__ Whh2, const float* __restrict__ bhh2,
    const float* __restrict__ W1,   const float* __restrict__ b1,
    const float* __restrict__ W2,   const float* __restrict__ b2,
    float* __restrict__ out)
{
    __shared__ __align__(16) _Float16 pub0[2 * NB * K * HID];
    __shared__ __align__(16) _Float16 pub1[2 * NB * K * HID];
    __shared__ float h2f[NB][HID];
    __shared__ float mbuf[NB][HID];

    const int lane = threadIdx.x & 63;

    // probe DPP row_ror direction
    const int d0 = __builtin_amdgcn_readfirstlane(rr<2>(lane));
    const int dir = (d0 == 2) ? 1 : -1;

#if __has_builtin(__builtin_amdgcn_permlane16_swap)
    uint2v sw = __builtin_amdgcn_permlane16_swap((unsigned)lane, (unsigned)lane,
                                                 false, false);
    const int s0  = __builtin_amdgcn_readlane((int)sw.x, 0);
    const int s16 = __builtin_amdgcn_readlane((int)sw.x, 16);
    const bool ok   = (s0 == 0 && s16 == 0) || (s0 == 16 && s16 == 16);
    const bool flip = (s0 == 16);
    if (ok) {
        run_rnn<false>(x, h_in, Wih0, bih0, Whh0, bhh0, Wih1, bih1, Whh1, bhh1,
                       Wih2, bih2, Whh2, bhh2, W1, b1, W2, b2, out,
                       dir, flip, pub0, pub1, h2f, mbuf);
    } else {
        run_rnn<true>(x, h_in, Wih0, bih0, Whh0, bhh0, Wih1, bih1, Whh1, bhh1,
                      Wih2, bih2, Whh2, bhh2, W1, b1, W2, b2, out,
                      dir, false, pub0, pub1, h2f, mbuf);
    }
#else
    run_rnn<true>(x, h_in, Wih0, bih0, Whh0, bhh0, Wih1, bih1, Whh1, bhh1,
                  Wih2, bih2, Whh2, bhh2, W1, b1, W2, b2, out,
                  dir, false, pub0, pub1, h2f, mbuf);
#endif
}

extern "C" void kernel_launch(void* const* d_in, const int* in_sizes, int n_in,
                              void* d_out, int out_size, void* d_ws, size_t ws_size,
                              hipStream_t stream) {
    const float* x    = (const float*)d_in[0];
    const float* h_in = (const float*)d_in[1];
    const float* Wih0 = (const float*)d_in[2];
    const float* bih0 = (const float*)d_in[3];
    const float* Whh0 = (const float*)d_in[4];
    const float* bhh0 = (const float*)d_in[5];
    const float* Wih1 = (const float*)d_in[6];
    const float* bih1 = (const float*)d_in[7];
    const float* Whh1 = (const float*)d_in[8];
    const float* bhh1 = (const float*)d_in[9];
    const float* Wih2 = (const float*)d_in[10];
    const float* bih2 = (const float*)d_in[11];
    const float* Whh2 = (const float*)d_in[12];
    const float* bhh2 = (const float*)d_in[13];
    const float* W1   = (const float*)d_in[14];
    const float* b1   = (const float*)d_in[15];
    const float* W2   = (const float*)d_in[16];
    const float* b2   = (const float*)d_in[17];
    float* out = (float*)d_out;

    dim3 grid(BATCH / NB);   // 512 blocks -> 2 blocks/CU, 6 waves/CU
    dim3 block(TPB);         // 3 waves (wave == layer)
    hipLaunchKernelGGL(rnn_hyb_kernel, grid, block, 0, stream,
                       x, h_in, Wih0, bih0, Whh0, bhh0,
                       Wih1, bih1, Whh1, bhh1, Wih2, bih2, Whh2, bhh2,
                       W1, b1, W2, b2, out);
}